// Round 3
// baseline (138.999 us; speedup 1.0000x reference)
//
#include <hip/hip_runtime.h>
#include <hip/hip_bf16.h>

#define LSEQ 4096
#define HDIM 256
#define NS   64
#define PC   32    // number of chunks
#define MC   128   // chunk length (PC*MC == LSEQ)

typedef __attribute__((ext_vector_type(8))) short short8;
typedef __attribute__((ext_vector_type(4))) float floatx4;

__device__ __forceinline__ float lane_bcast(float v, int j) {
    return __uint_as_float(__builtin_amdgcn_readlane(__float_as_uint(v), j));
}

// ---------------- LayerNorm stats (blocks 0..4095) + W->bf16 conv (blocks 4096..4159) ----
__global__ __launch_bounds__(256) void k_ln_stats(const float* __restrict__ x,
                                                  float* __restrict__ mu,
                                                  float* __restrict__ rstd,
                                                  const float* __restrict__ W1,
                                                  const float* __restrict__ W2,
                                                  unsigned short* __restrict__ w1b,
                                                  unsigned short* __restrict__ w2b) {
    int t = threadIdx.x;
    if (blockIdx.x >= LSEQ) {   // weight conversion tail blocks
        int g = (blockIdx.x - LSEQ) * 256 + t;   // 16384 threads, 4 elems each
        float4 a = ((const float4*)W1)[g];
        float4 c = ((const float4*)W2)[g];
        ushort4 o1, o2;
        __hip_bfloat16 h;
        h = __float2bfloat16(a.x); o1.x = *(unsigned short*)&h;
        h = __float2bfloat16(a.y); o1.y = *(unsigned short*)&h;
        h = __float2bfloat16(a.z); o1.z = *(unsigned short*)&h;
        h = __float2bfloat16(a.w); o1.w = *(unsigned short*)&h;
        h = __float2bfloat16(c.x); o2.x = *(unsigned short*)&h;
        h = __float2bfloat16(c.y); o2.y = *(unsigned short*)&h;
        h = __float2bfloat16(c.z); o2.z = *(unsigned short*)&h;
        h = __float2bfloat16(c.w); o2.w = *(unsigned short*)&h;
        ((ushort4*)w1b)[g] = o1;
        ((ushort4*)w2b)[g] = o2;
        return;
    }
    int l = blockIdx.x;
    float v = x[l * HDIM + t];
    float s = v, s2 = v * v;
#pragma unroll
    for (int o = 32; o; o >>= 1) {
        s  += __shfl_xor(s, o);
        s2 += __shfl_xor(s2, o);
    }
    __shared__ float ps[4], ps2[4];
    int w = t >> 6;
    if ((t & 63) == 0) { ps[w] = s; ps2[w] = s2; }
    __syncthreads();
    if (t == 0) {
        float S = ps[0] + ps[1] + ps[2] + ps[3];
        float S2 = ps2[0] + ps2[1] + ps2[2] + ps2[3];
        float m = S * (1.0f / HDIM);
        float var = S2 * (1.0f / HDIM) - m * m;
        mu[l] = m;
        rstd[l] = rsqrtf(var + 1e-5f);
    }
}

// ------------- normalize + transpose to xnT[H][L] (coalesced both ways) -------------
__global__ __launch_bounds__(256) void k_transnorm(const float* __restrict__ x,
                                                   const float* __restrict__ mu,
                                                   const float* __restrict__ rstd,
                                                   const float* __restrict__ w,
                                                   const float* __restrict__ b,
                                                   float* __restrict__ xnT) {
    __shared__ float tile[64 * 65];
    int l0 = blockIdx.x * 64, h0 = blockIdx.y * 64;
    int t = threadIdx.x;
#pragma unroll
    for (int i = 0; i < 16; ++i) {
        int e = i * 256 + t;
        int r = e >> 6, c = e & 63;          // r: l-offset, c: h-offset
        int l = l0 + r, h = h0 + c;
        float v = x[l * HDIM + h];
        v = (v - mu[l]) * rstd[l] * w[h] + b[h];
        tile[c * 65 + r] = v;                // store transposed: tile[h][l]
    }
    __syncthreads();
#pragma unroll
    for (int i = 0; i < 16; ++i) {
        int e = i * 256 + t;
        int hh = e >> 6, ll = e & 63;
        xnT[(size_t)(h0 + hh) * LSEQ + l0 + ll] = tile[hh * 65 + ll];
    }
}

// ---------------- shared constant computation ----------------
__device__ inline void ssm_consts(const float* Lre, const float* Lim,
                                  const float* Bre, const float* Bim,
                                  const float* lstep, int h, int n,
                                  float& are, float& aim, float& bre, float& bim) {
    int idx = h * NS + n;
    float lre = Lre[idx], lim = Lim[idx];
    float dt = expf(lstep[h]);
    float er = expf(lre * dt);
    float sa, ca;
    sincosf(lim * dt, &sa, &ca);
    are = er * ca; aim = er * sa;
    // T = (Ab - 1) / Lam
    float inv = 1.0f / (lre * lre + lim * lim);
    float nre = are - 1.0f, nim = aim;
    float tre = (nre * lre + nim * lim) * inv;
    float tim = (nim * lre - nre * lim) * inv;
    float br = Bre[idx], bi = Bim[idx];
    bre = tre * br - tim * bi;
    bim = tre * bi + tim * br;
}

// ---------------- pass 1: chunk-local scan from zero state ----------------
// 4 waves/block, one chunk per wave. Input broadcast via readlane (no mem waits).
__global__ __launch_bounds__(256) void k_scan_local(const float* __restrict__ xnT,
                                                    const float* __restrict__ Lre,
                                                    const float* __restrict__ Lim,
                                                    const float* __restrict__ Bre,
                                                    const float* __restrict__ Bim,
                                                    const float* __restrict__ lstep,
                                                    float2* __restrict__ f) {
    int wv = __builtin_amdgcn_readfirstlane((int)threadIdx.x) >> 6;  // uniform wave id
    int n = threadIdx.x & 63;
    int c = blockIdx.x * 4 + wv, h = blockIdx.y;
    const float* u = xnT + (size_t)h * LSEQ + c * MC;
    float are, aim, bre, bim;
    ssm_consts(Lre, Lim, Bre, Bim, lstep, h, n, are, aim, bre, bim);
    float sre = 0.f, sim = 0.f;
    for (int g = 0; g < 2; ++g) {
        float uv = u[g * 64 + n];            // coalesced vector load, lane j holds u[j]
#pragma unroll
        for (int j = 0; j < 64; ++j) {
            float us = lane_bcast(uv, j);    // VALU broadcast, no memory
            float nr = fmaf(are, sre, fmaf(-aim, sim, bre * us));
            float ni = fmaf(are, sim, fmaf( aim, sre, bim * us));
            sre = nr; sim = ni;
        }
    }
    f[(size_t)(h * PC + c) * NS + n] = make_float2(sre, sim);
}

// ---------------- pass 2: seeded scan (self chunk-scan over f), y, gelu, g bf16 [L][H],
// and hidden state for the last chunk. 4 waves/block, one chunk per wave.
__global__ __launch_bounds__(256) void k_scan_out(const float* __restrict__ xnT,
                                                  const float* __restrict__ Lre,
                                                  const float* __restrict__ Lim,
                                                  const float* __restrict__ Bre,
                                                  const float* __restrict__ Bim,
                                                  const float* __restrict__ Cre,
                                                  const float* __restrict__ Cim,
                                                  const float* __restrict__ Dv,
                                                  const float* __restrict__ lstep,
                                                  const float2* __restrict__ f,
                                                  __hip_bfloat16* __restrict__ gb,
                                                  float* __restrict__ hid,
                                                  int interleaved) {
    __shared__ __align__(16) float red[4][16 * 68];
    int wv = __builtin_amdgcn_readfirstlane((int)threadIdx.x) >> 6;  // uniform wave id
    int lane = threadIdx.x & 63;
    int c = blockIdx.x * 4 + wv, h = blockIdx.y, n = lane;
    const float* u = xnT + (size_t)h * LSEQ + c * MC;
    float are, aim, bre, bim;
    ssm_consts(Lre, Lim, Bre, Bim, lstep, h, n, are, aim, bre, bim);
    int idx = h * NS + n;
    float cre = Cre[idx], cim = Cim[idx];
    float Dh = Dv[h];

    // ---- chunk-scan: s0 for this chunk from f[h][0..c-1] with multiplier Ab^128 ----
    float ar = are, ai = aim;
#pragma unroll
    for (int q = 0; q < 7; ++q) {   // Ab^128 by repeated squaring
        float r2 = ar * ar - ai * ai;
        ai = 2.f * ar * ai;
        ar = r2;
    }
    float sre = 0.f, sim = 0.f;
    for (int cp = 0; cp < c; ++cp) {
        float2 fc = f[(size_t)(h * PC + cp) * NS + n];   // coalesced 512B
        float nr = fmaf(ar, sre, fmaf(-ai, sim, fc.x));
        float ni = fmaf(ar, sim, fmaf( ai, sre, fc.y));
        sre = nr; sim = ni;
    }

    float* rw = red[wv];
    int t16 = lane & 15, p = lane >> 4;

    for (int g = 0; g < 2; ++g) {
        float uv = u[g * 64 + lane];         // coalesced; lane j holds token g*64+j
#pragma unroll
        for (int jg = 0; jg < 4; ++jg) {     // 4 groups of 16 tokens
#pragma unroll
            for (int tt = 0; tt < 16; ++tt) {
                float us = lane_bcast(uv, jg * 16 + tt);
                float nr = fmaf(are, sre, fmaf(-aim, sim, bre * us));
                float ni = fmaf(are, sim, fmaf( aim, sre, bim * us));
                sre = nr; sim = ni;
                rw[tt * 68 + n] = fmaf(cre, sre, -(cim * sim));
            }
            // lane (t16,p) sums n in [16p,16p+16) for token t16, then combine over p
            float a0 = 0.f;
            const float4* rp = (const float4*)(rw + t16 * 68 + p * 16);
#pragma unroll
            for (int qq = 0; qq < 4; ++qq) {
                float4 v = rp[qq];
                a0 += (v.x + v.y) + (v.z + v.w);
            }
            a0 += __shfl_xor(a0, 16);
            a0 += __shfl_xor(a0, 32);
            float u_tok = __shfl(uv, jg * 16 + t16);   // token value for lanes<16
            if (lane < 16) {
                int l = c * MC + g * 64 + jg * 16 + t16;
                float y = fmaf(2.f, a0, Dh * u_tok);
                // tanh-approx gelu (jax.nn.gelu default)
                float z = 0.7978845608028654f * fmaf(0.044715f, y * y * y, y);
                float e = __expf(2.f * z);
                float th = 1.f - 2.f / (e + 1.f);
                float gg = 0.5f * y * (1.f + th);
                gb[(size_t)l * HDIM + h] = __float2bfloat16(gg);
            }
        }
    }

    if (c == PC - 1) {   // final state after all 4096 tokens == hidden
        if (interleaved) {
            ((float2*)hid)[idx] = make_float2(sre, sim);
        } else {
            hid[idx] = sre;
        }
    }
}

// ---------------- GLU epilogue via MFMA, LDS-free ----------------
// One wave per block computes a 32(l) x 32(h) out tile for BOTH GEMMs.
__global__ __launch_bounds__(64) void k_glu_mfma(const unsigned short* __restrict__ gbs,
                                                 const unsigned short* __restrict__ w1b,
                                                 const unsigned short* __restrict__ w2b,
                                                 const float* __restrict__ b1v,
                                                 const float* __restrict__ b2v,
                                                 const float* __restrict__ x,
                                                 float* __restrict__ out) {
    int bx = blockIdx.x;
    int m0 = (bx >> 3) * 32;        // 128 m-tiles
    int n0 = (bx & 7) * 32;         // 8 n-tiles
    int lane = threadIdx.x;
    int t = lane & 15, q = lane >> 4;

    floatx4 acc[2][2][2];           // [mt][nt][{W1,W2}]
#pragma unroll
    for (int a = 0; a < 2; ++a)
#pragma unroll
        for (int b = 0; b < 2; ++b)
#pragma unroll
            for (int g = 0; g < 2; ++g)
                acc[a][b][g] = (floatx4){0.f, 0.f, 0.f, 0.f};

    const unsigned short* A0  = gbs + (size_t)(m0 + t) * HDIM + q * 8;
    const unsigned short* A1  = A0 + 16 * HDIM;
    const unsigned short* B10 = w1b + (size_t)(n0 + t) * HDIM + q * 8;
    const unsigned short* B11 = B10 + 16 * HDIM;
    const unsigned short* B20 = w2b + (size_t)(n0 + t) * HDIM + q * 8;
    const unsigned short* B21 = B20 + 16 * HDIM;

#pragma unroll
    for (int ks = 0; ks < 8; ++ks) {
        int off = ks * 32;
        short8 a0  = *(const short8*)(A0  + off);
        short8 a1  = *(const short8*)(A1  + off);
        short8 b10 = *(const short8*)(B10 + off);
        short8 b11 = *(const short8*)(B11 + off);
        short8 b20 = *(const short8*)(B20 + off);
        short8 b21 = *(const short8*)(B21 + off);
        acc[0][0][0] = __builtin_amdgcn_mfma_f32_16x16x32_bf16(a0, b10, acc[0][0][0], 0, 0, 0);
        acc[0][1][0] = __builtin_amdgcn_mfma_f32_16x16x32_bf16(a0, b11, acc[0][1][0], 0, 0, 0);
        acc[1][0][0] = __builtin_amdgcn_mfma_f32_16x16x32_bf16(a1, b10, acc[1][0][0], 0, 0, 0);
        acc[1][1][0] = __builtin_amdgcn_mfma_f32_16x16x32_bf16(a1, b11, acc[1][1][0], 0, 0, 0);
        acc[0][0][1] = __builtin_amdgcn_mfma_f32_16x16x32_bf16(a0, b20, acc[0][0][1], 0, 0, 0);
        acc[0][1][1] = __builtin_amdgcn_mfma_f32_16x16x32_bf16(a0, b21, acc[0][1][1], 0, 0, 0);
        acc[1][0][1] = __builtin_amdgcn_mfma_f32_16x16x32_bf16(a1, b20, acc[1][0][1], 0, 0, 0);
        acc[1][1][1] = __builtin_amdgcn_mfma_f32_16x16x32_bf16(a1, b21, acc[1][1][1], 0, 0, 0);
    }

#pragma unroll
    for (int nt = 0; nt < 2; ++nt) {
        int hh = n0 + nt * 16 + t;
        float bb1 = b1v[hh], bb2 = b2v[hh];
#pragma unroll
        for (int mt = 0; mt < 2; ++mt) {
#pragma unroll
            for (int reg = 0; reg < 4; ++reg) {
                int l = m0 + mt * 16 + q * 4 + reg;   // C/D: row=(lane>>4)*4+reg, col=lane&15
                float a  = acc[mt][nt][0][reg] + bb1;
                float sg = 1.f / (1.f + __expf(-(acc[mt][nt][1][reg] + bb2)));
                out[(size_t)l * HDIM + hh] = fmaf(a, sg, x[(size_t)l * HDIM + hh]);
            }
        }
    }
}

extern "C" void kernel_launch(void* const* d_in, const int* in_sizes, int n_in,
                              void* d_out, int out_size, void* d_ws, size_t ws_size,
                              hipStream_t stream) {
    (void)in_sizes; (void)n_in; (void)ws_size;
    const float* x     = (const float*)d_in[0];
    const float* Lre   = (const float*)d_in[1];
    const float* Lim   = (const float*)d_in[2];
    const float* Bre   = (const float*)d_in[3];
    const float* Bim   = (const float*)d_in[4];
    const float* Cre   = (const float*)d_in[5];
    const float* Cim   = (const float*)d_in[6];
    const float* Dv    = (const float*)d_in[7];
    const float* lstep = (const float*)d_in[8];
    const float* lnw   = (const float*)d_in[9];
    const float* lnb   = (const float*)d_in[10];
    const float* W1    = (const float*)d_in[11];
    const float* b1    = (const float*)d_in[12];
    const float* W2    = (const float*)d_in[13];
    const float* b2    = (const float*)d_in[14];

    float* ws   = (float*)d_ws;
    float* mu   = ws;                          // L
    float* rstd = ws + LSEQ;                   // L
    float* xnT  = ws + 2 * LSEQ;               // H*L
    float2* f   = (float2*)(xnT + (size_t)HDIM * LSEQ);  // H*PC*NS float2
    unsigned short* gb  = (unsigned short*)(f + (size_t)HDIM * PC * NS);  // L*H bf16
    unsigned short* w1b = gb + (size_t)LSEQ * HDIM;      // H*H bf16
    unsigned short* w2b = w1b + HDIM * HDIM;             // H*H bf16

    int interleaved = (out_size == LSEQ * HDIM + 2 * HDIM * NS) ? 1 : 0;
    float* hid  = (float*)d_out;
    float* outp = (float*)d_out + (interleaved ? 2 * HDIM * NS : HDIM * NS);

    k_ln_stats   <<<LSEQ + 64, 256, 0, stream>>>(x, mu, rstd, W1, W2, w1b, w2b);
    k_transnorm  <<<dim3(LSEQ / 64, HDIM / 64), 256, 0, stream>>>(x, mu, rstd, lnw, lnb, xnT);
    k_scan_local <<<dim3(PC / 4, HDIM), 256, 0, stream>>>(xnT, Lre, Lim, Bre, Bim, lstep, f);
    k_scan_out   <<<dim3(PC / 4, HDIM), 256, 0, stream>>>(xnT, Lre, Lim, Bre, Bim, Cre, Cim,
                                                          Dv, lstep, f, (__hip_bfloat16*)gb,
                                                          hid, interleaved);
    k_glu_mfma   <<<128 * 8, 64, 0, stream>>>(gb, w1b, w2b, b1, b2, x, outp);
}

// Round 4
// 135.927 us; speedup vs baseline: 1.0226x; 1.0226x over previous
//
#include <hip/hip_runtime.h>
#include <hip/hip_bf16.h>

#define LSEQ 4096
#define HDIM 256
#define NS   64
#define PC   32    // number of chunks
#define MC   128   // chunk length (PC*MC == LSEQ)

typedef __attribute__((ext_vector_type(8))) short short8;
typedef __attribute__((ext_vector_type(4))) float floatx4;

__device__ __forceinline__ float lane_bcast(float v, int j) {
    return __uint_as_float(__builtin_amdgcn_readlane(__float_as_uint(v), j));
}

// ---------------- fused LN (stats+normalize+transpose) + W->bf16 conv ----------------
// blocks 0..255: LN for 16 tokens each; blocks 256..319: weight conversion.
__global__ __launch_bounds__(256) void k_pre(const float* __restrict__ x,
                                             const float* __restrict__ lnw,
                                             const float* __restrict__ lnb,
                                             const float* __restrict__ W1,
                                             const float* __restrict__ W2,
                                             float* __restrict__ xnT,
                                             unsigned short* __restrict__ w1b,
                                             unsigned short* __restrict__ w2b) {
    int t = threadIdx.x;
    if (blockIdx.x >= 256) {   // weight conversion tail blocks
        int g = (blockIdx.x - 256) * 256 + t;   // 16384 float4s each of W1,W2
        float4 a = ((const float4*)W1)[g];
        float4 c = ((const float4*)W2)[g];
        ushort4 o1, o2;
        __hip_bfloat16 hh;
        hh = __float2bfloat16(a.x); o1.x = *(unsigned short*)&hh;
        hh = __float2bfloat16(a.y); o1.y = *(unsigned short*)&hh;
        hh = __float2bfloat16(a.z); o1.z = *(unsigned short*)&hh;
        hh = __float2bfloat16(a.w); o1.w = *(unsigned short*)&hh;
        hh = __float2bfloat16(c.x); o2.x = *(unsigned short*)&hh;
        hh = __float2bfloat16(c.y); o2.y = *(unsigned short*)&hh;
        hh = __float2bfloat16(c.z); o2.z = *(unsigned short*)&hh;
        hh = __float2bfloat16(c.w); o2.w = *(unsigned short*)&hh;
        ((ushort4*)w1b)[g] = o1;
        ((ushort4*)w2b)[g] = o2;
        return;
    }
    __shared__ float tile[16][257];
    __shared__ float smu[16], srs[16];
    int l0 = blockIdx.x * 16;
#pragma unroll
    for (int i = 0; i < 16; ++i)
        tile[i][t] = x[(size_t)(l0 + i) * HDIM + t];   // coalesced
    __syncthreads();
    int wv = t >> 6, lane = t & 63;
#pragma unroll
    for (int k = 0; k < 4; ++k) {
        int i = wv * 4 + k;
        float s = 0.f, s2 = 0.f;
#pragma unroll
        for (int q = 0; q < 4; ++q) {
            float v = tile[i][lane + 64 * q];
            s += v; s2 += v * v;
        }
#pragma unroll
        for (int o = 32; o; o >>= 1) {
            s  += __shfl_xor(s, o);
            s2 += __shfl_xor(s2, o);
        }
        if (lane == 0) {
            float m = s * (1.0f / HDIM);
            smu[i] = m;
            srs[i] = rsqrtf(s2 * (1.0f / HDIM) - m * m + 1e-5f);
        }
    }
    __syncthreads();
    // thread t == feature h; write xnT[h][l0..l0+16) contiguous
    float wh = lnw[t], bh = lnb[t];
    float o[16];
#pragma unroll
    for (int i = 0; i < 16; ++i)
        o[i] = (tile[i][t] - smu[i]) * srs[i] * wh + bh;
    float4* dst = (float4*)(xnT + (size_t)t * LSEQ + l0);
#pragma unroll
    for (int k = 0; k < 4; ++k)
        dst[k] = make_float4(o[4 * k], o[4 * k + 1], o[4 * k + 2], o[4 * k + 3]);
}

// ---------------- shared constant computation ----------------
__device__ inline void ssm_consts(const float* Lre, const float* Lim,
                                  const float* Bre, const float* Bim,
                                  const float* lstep, int h, int n,
                                  float& are, float& aim, float& bre, float& bim) {
    int idx = h * NS + n;
    float lre = Lre[idx], lim = Lim[idx];
    float dt = expf(lstep[h]);
    float er = expf(lre * dt);
    float sa, ca;
    sincosf(lim * dt, &sa, &ca);
    are = er * ca; aim = er * sa;
    // T = (Ab - 1) / Lam
    float inv = 1.0f / (lre * lre + lim * lim);
    float nre = are - 1.0f, nim = aim;
    float tre = (nre * lre + nim * lim) * inv;
    float tim = (nim * lre - nre * lim) * inv;
    float br = Bre[idx], bi = Bim[idx];
    bre = tre * br - tim * bi;
    bim = tre * bi + tim * br;
}

// ---------------- fused 3-phase scan: one block per h (16 waves) ----------------
// phase 1: per-wave local chunk scans -> f in LDS
// phase 2: wave 0 scans the 32 chunk states (emits hidden)
// phase 3: seeded scans + y reduction + gelu -> gb[l][h] bf16
__global__ __launch_bounds__(1024) void k_scan(const float* __restrict__ xnT,
                                               const float* __restrict__ Lre,
                                               const float* __restrict__ Lim,
                                               const float* __restrict__ Bre,
                                               const float* __restrict__ Bim,
                                               const float* __restrict__ Cre,
                                               const float* __restrict__ Cim,
                                               const float* __restrict__ Dv,
                                               const float* __restrict__ lstep,
                                               __hip_bfloat16* __restrict__ gb,
                                               float* __restrict__ hid,
                                               int interleaved) {
    __shared__ float2 fst[PC * NS];            // 16 KB: f, then s0 in-place
    __shared__ __align__(16) float red[16][8 * 68];  // 34.8 KB: per-wave reduce buf
    int h = blockIdx.x;
    int wv = __builtin_amdgcn_readfirstlane((int)threadIdx.x) >> 6;  // uniform wave id
    int lane = threadIdx.x & 63, n = lane;
    const float* uh = xnT + (size_t)h * LSEQ;

    float are, aim, bre, bim;
    ssm_consts(Lre, Lim, Bre, Bim, lstep, h, n, are, aim, bre, bim);
    int idx = h * NS + n;
    float cre = Cre[idx], cim = Cim[idx];
    float Dh = Dv[h];

    // ---- phase 1: local scans (wave wv handles chunks 2wv, 2wv+1) ----
#pragma unroll
    for (int cc = 0; cc < 2; ++cc) {
        int c = wv * 2 + cc;
        const float* u = uh + c * MC;
        float sre = 0.f, sim = 0.f;
        for (int g = 0; g < 2; ++g) {
            float uv = u[g * 64 + lane];        // coalesced; lane j holds token g*64+j
#pragma unroll
            for (int j = 0; j < 64; ++j) {
                float us = lane_bcast(uv, j);
                float nr = fmaf(are, sre, fmaf(-aim, sim, bre * us));
                float ni = fmaf(are, sim, fmaf( aim, sre, bim * us));
                sre = nr; sim = ni;
            }
        }
        fst[c * NS + n] = make_float2(sre, sim);
    }
    __syncthreads();

    // ---- phase 2: chunk-level scan by wave 0; emits hidden ----
    if (wv == 0) {
        float ar = are, ai = aim;
#pragma unroll
        for (int q = 0; q < 7; ++q) {   // Ab^128 by repeated squaring
            float r2 = ar * ar - ai * ai;
            ai = 2.f * ar * ai;
            ar = r2;
        }
        float sre = 0.f, sim = 0.f;
        for (int c = 0; c < PC; ++c) {
            float2 fc = fst[c * NS + n];
            fst[c * NS + n] = make_float2(sre, sim);   // s0 = state before chunk c
            float nr = fmaf(ar, sre, fmaf(-ai, sim, fc.x));
            float ni = fmaf(ar, sim, fmaf( ai, sre, fc.y));
            sre = nr; sim = ni;
        }
        if (interleaved) {
            ((float2*)hid)[idx] = make_float2(sre, sim);
        } else {
            hid[idx] = sre;
        }
    }
    __syncthreads();

    // ---- phase 3: seeded scans + projection + gelu ----
    float* rw = red[wv];
    int t8 = lane & 7, p = lane >> 3;
#pragma unroll
    for (int cc = 0; cc < 2; ++cc) {
        int c = wv * 2 + cc;
        const float* u = uh + c * MC;
        float2 s00 = fst[c * NS + n];
        float sre = s00.x, sim = s00.y;
        for (int g = 0; g < 2; ++g) {
            float uv = u[g * 64 + lane];
#pragma unroll
            for (int jg = 0; jg < 8; ++jg) {     // 8 groups of 8 tokens
#pragma unroll
                for (int tt = 0; tt < 8; ++tt) {
                    float us = lane_bcast(uv, jg * 8 + tt);
                    float nr = fmaf(are, sre, fmaf(-aim, sim, bre * us));
                    float ni = fmaf(are, sim, fmaf( aim, sre, bim * us));
                    sre = nr; sim = ni;
                    rw[tt * 68 + n] = fmaf(cre, sre, -(cim * sim));
                }
                // lane (t8,p) sums n in [8p, 8p+8) for token t8, combine over p
                const float4* rp = (const float4*)(rw + t8 * 68 + p * 8);
                float4 v0 = rp[0], v1 = rp[1];
                float a0 = ((v0.x + v0.y) + (v0.z + v0.w)) +
                           ((v1.x + v1.y) + (v1.z + v1.w));
                a0 += __shfl_xor(a0, 8);
                a0 += __shfl_xor(a0, 16);
                a0 += __shfl_xor(a0, 32);
                float u_tok = __shfl(uv, jg * 8 + t8);
                if (lane < 8) {
                    int l = c * MC + g * 64 + jg * 8 + t8;
                    float y = fmaf(2.f, a0, Dh * u_tok);
                    // tanh-approx gelu (jax.nn.gelu default)
                    float z = 0.7978845608028654f * fmaf(0.044715f, y * y * y, y);
                    float e = __expf(2.f * z);
                    float th = 1.f - 2.f / (e + 1.f);
                    float gg = 0.5f * y * (1.f + th);
                    gb[(size_t)l * HDIM + h] = __float2bfloat16(gg);
                }
            }
        }
    }
}

// ---------------- GLU epilogue via MFMA, LDS-free ----------------
// One wave per block computes a 32(l) x 32(h) out tile for BOTH GEMMs.
__global__ __launch_bounds__(64) void k_glu_mfma(const unsigned short* __restrict__ gbs,
                                                 const unsigned short* __restrict__ w1b,
                                                 const unsigned short* __restrict__ w2b,
                                                 const float* __restrict__ b1v,
                                                 const float* __restrict__ b2v,
                                                 const float* __restrict__ x,
                                                 float* __restrict__ out) {
    int bx = blockIdx.x;
    int m0 = (bx >> 3) * 32;        // 128 m-tiles
    int n0 = (bx & 7) * 32;         // 8 n-tiles
    int lane = threadIdx.x;
    int t = lane & 15, q = lane >> 4;

    floatx4 acc[2][2][2];           // [mt][nt][{W1,W2}]
#pragma unroll
    for (int a = 0; a < 2; ++a)
#pragma unroll
        for (int b = 0; b < 2; ++b)
#pragma unroll
            for (int g = 0; g < 2; ++g)
                acc[a][b][g] = (floatx4){0.f, 0.f, 0.f, 0.f};

    const unsigned short* A0  = gbs + (size_t)(m0 + t) * HDIM + q * 8;
    const unsigned short* A1  = A0 + 16 * HDIM;
    const unsigned short* B10 = w1b + (size_t)(n0 + t) * HDIM + q * 8;
    const unsigned short* B11 = B10 + 16 * HDIM;
    const unsigned short* B20 = w2b + (size_t)(n0 + t) * HDIM + q * 8;
    const unsigned short* B21 = B20 + 16 * HDIM;

#pragma unroll
    for (int ks = 0; ks < 8; ++ks) {
        int off = ks * 32;
        short8 a0  = *(const short8*)(A0  + off);
        short8 a1  = *(const short8*)(A1  + off);
        short8 b10 = *(const short8*)(B10 + off);
        short8 b11 = *(const short8*)(B11 + off);
        short8 b20 = *(const short8*)(B20 + off);
        short8 b21 = *(const short8*)(B21 + off);
        acc[0][0][0] = __builtin_amdgcn_mfma_f32_16x16x32_bf16(a0, b10, acc[0][0][0], 0, 0, 0);
        acc[0][1][0] = __builtin_amdgcn_mfma_f32_16x16x32_bf16(a0, b11, acc[0][1][0], 0, 0, 0);
        acc[1][0][0] = __builtin_amdgcn_mfma_f32_16x16x32_bf16(a1, b10, acc[1][0][0], 0, 0, 0);
        acc[1][1][0] = __builtin_amdgcn_mfma_f32_16x16x32_bf16(a1, b11, acc[1][1][0], 0, 0, 0);
        acc[0][0][1] = __builtin_amdgcn_mfma_f32_16x16x32_bf16(a0, b20, acc[0][0][1], 0, 0, 0);
        acc[0][1][1] = __builtin_amdgcn_mfma_f32_16x16x32_bf16(a0, b21, acc[0][1][1], 0, 0, 0);
        acc[1][0][1] = __builtin_amdgcn_mfma_f32_16x16x32_bf16(a1, b20, acc[1][0][1], 0, 0, 0);
        acc[1][1][1] = __builtin_amdgcn_mfma_f32_16x16x32_bf16(a1, b21, acc[1][1][1], 0, 0, 0);
    }

#pragma unroll
    for (int nt = 0; nt < 2; ++nt) {
        int hh = n0 + nt * 16 + t;
        float bb1 = b1v[hh], bb2 = b2v[hh];
#pragma unroll
        for (int mt = 0; mt < 2; ++mt) {
#pragma unroll
            for (int reg = 0; reg < 4; ++reg) {
                int l = m0 + mt * 16 + q * 4 + reg;   // C/D: row=(lane>>4)*4+reg, col=lane&15
                float a  = acc[mt][nt][0][reg] + bb1;
                float sg = 1.f / (1.f + __expf(-(acc[mt][nt][1][reg] + bb2)));
                out[(size_t)l * HDIM + hh] = fmaf(a, sg, x[(size_t)l * HDIM + hh]);
            }
        }
    }
}

extern "C" void kernel_launch(void* const* d_in, const int* in_sizes, int n_in,
                              void* d_out, int out_size, void* d_ws, size_t ws_size,
                              hipStream_t stream) {
    (void)in_sizes; (void)n_in; (void)ws_size;
    const float* x     = (const float*)d_in[0];
    const float* Lre   = (const float*)d_in[1];
    const float* Lim   = (const float*)d_in[2];
    const float* Bre   = (const float*)d_in[3];
    const float* Bim   = (const float*)d_in[4];
    const float* Cre   = (const float*)d_in[5];
    const float* Cim   = (const float*)d_in[6];
    const float* Dv    = (const float*)d_in[7];
    const float* lstep = (const float*)d_in[8];
    const float* lnw   = (const float*)d_in[9];
    const float* lnb   = (const float*)d_in[10];
    const float* W1    = (const float*)d_in[11];
    const float* b1    = (const float*)d_in[12];
    const float* W2    = (const float*)d_in[13];
    const float* b2    = (const float*)d_in[14];

    float* ws   = (float*)d_ws;
    float* xnT  = ws;                                     // H*L fp32
    unsigned short* gb  = (unsigned short*)(xnT + (size_t)HDIM * LSEQ);  // L*H bf16
    unsigned short* w1b = gb + (size_t)LSEQ * HDIM;       // H*H bf16
    unsigned short* w2b = w1b + HDIM * HDIM;              // H*H bf16

    int interleaved = (out_size == LSEQ * HDIM + 2 * HDIM * NS) ? 1 : 0;
    float* hid  = (float*)d_out;
    float* outp = (float*)d_out + (interleaved ? 2 * HDIM * NS : HDIM * NS);

    k_pre      <<<256 + 64, 256, 0, stream>>>(x, lnw, lnb, W1, W2, xnT, w1b, w2b);
    k_scan     <<<HDIM, 1024, 0, stream>>>(xnT, Lre, Lim, Bre, Bim, Cre, Cim,
                                           Dv, lstep, (__hip_bfloat16*)gb, hid, interleaved);
    k_glu_mfma <<<128 * 8, 64, 0, stream>>>(gb, w1b, w2b, b1, b2, x, outp);
}

// Round 5
// 122.890 us; speedup vs baseline: 1.1311x; 1.1061x over previous
//
#include <hip/hip_runtime.h>
#include <hip/hip_bf16.h>

#define LSEQ 4096
#define HDIM 256
#define NS   64
#define PC   32    // number of chunks
#define MC   128   // chunk length (PC*MC == LSEQ)

typedef __attribute__((ext_vector_type(8))) short short8;
typedef __attribute__((ext_vector_type(4))) float floatx4;

__device__ __forceinline__ short b16(float x) {
    __hip_bfloat16 h = __float2bfloat16(x);
    return *(reinterpret_cast<short*>(&h));
}
__device__ __forceinline__ unsigned int pk2(float a, float b) {
    return (unsigned int)(unsigned short)b16(a) | ((unsigned int)(unsigned short)b16(b) << 16);
}
__device__ __forceinline__ void cmul(float& xr, float& xi, float yr, float yi) {
    float r = xr * yr - xi * yi;
    float i = xr * yi + xi * yr;
    xr = r; xi = i;
}

// ---------------- fused LN (stats+normalize+transpose) + W->bf16 conv ----------------
__global__ __launch_bounds__(256) void k_pre(const float* __restrict__ x,
                                             const float* __restrict__ lnw,
                                             const float* __restrict__ lnb,
                                             const float* __restrict__ W1,
                                             const float* __restrict__ W2,
                                             float* __restrict__ xnT,
                                             unsigned short* __restrict__ w1b,
                                             unsigned short* __restrict__ w2b) {
    int t = threadIdx.x;
    if (blockIdx.x >= 256) {   // weight conversion tail blocks
        int g = (blockIdx.x - 256) * 256 + t;
        float4 a = ((const float4*)W1)[g];
        float4 c = ((const float4*)W2)[g];
        ushort4 o1, o2;
        o1.x = (unsigned short)b16(a.x); o1.y = (unsigned short)b16(a.y);
        o1.z = (unsigned short)b16(a.z); o1.w = (unsigned short)b16(a.w);
        o2.x = (unsigned short)b16(c.x); o2.y = (unsigned short)b16(c.y);
        o2.z = (unsigned short)b16(c.z); o2.w = (unsigned short)b16(c.w);
        ((ushort4*)w1b)[g] = o1;
        ((ushort4*)w2b)[g] = o2;
        return;
    }
    __shared__ float tile[16][257];
    __shared__ float smu[16], srs[16];
    int l0 = blockIdx.x * 16;
#pragma unroll
    for (int i = 0; i < 16; ++i)
        tile[i][t] = x[(size_t)(l0 + i) * HDIM + t];
    __syncthreads();
    int wv = t >> 6, lane = t & 63;
#pragma unroll
    for (int k = 0; k < 4; ++k) {
        int i = wv * 4 + k;
        float s = 0.f, s2 = 0.f;
#pragma unroll
        for (int q = 0; q < 4; ++q) {
            float v = tile[i][lane + 64 * q];
            s += v; s2 += v * v;
        }
#pragma unroll
        for (int o = 32; o; o >>= 1) {
            s  += __shfl_xor(s, o);
            s2 += __shfl_xor(s2, o);
        }
        if (lane == 0) {
            float m = s * (1.0f / HDIM);
            smu[i] = m;
            srs[i] = rsqrtf(s2 * (1.0f / HDIM) - m * m + 1e-5f);
        }
    }
    __syncthreads();
    float wh = lnw[t], bh = lnb[t];
    float o[16];
#pragma unroll
    for (int i = 0; i < 16; ++i)
        o[i] = (tile[i][t] - smu[i]) * srs[i] * wh + bh;
    float4* dst = (float4*)(xnT + (size_t)t * LSEQ + l0);
#pragma unroll
    for (int k = 0; k < 4; ++k)
        dst[k] = make_float4(o[4 * k], o[4 * k + 1], o[4 * k + 2], o[4 * k + 3]);
}

// ---------------- shared constant computation ----------------
__device__ __forceinline__ void ssm_consts(const float* Lre, const float* Lim,
                                           const float* Bre, const float* Bim,
                                           float dt, int idx,
                                           float& are, float& aim, float& bre, float& bim) {
    float lre = Lre[idx], lim = Lim[idx];
    float er = expf(lre * dt);
    float sa, ca;
    sincosf(lim * dt, &sa, &ca);
    are = er * ca; aim = er * sa;
    float inv = 1.0f / (lre * lre + lim * lim);
    float nre = are - 1.0f, nim = aim;
    float tre = (nre * lre + nim * lim) * inv;
    float tim = (nim * lre - nre * lim) * inv;
    float br = Bre[idx], bi = Bim[idx];
    bre = tre * br - tim * bi;
    bim = tre * bi + tim * br;
}

// ---------------- MFMA-formulated SSM: one block (4 waves) per h ----------------
// y[t] = sum_{j<=t} K[t-j] u[j]  (Toeplitz GEMM)  + Re(E @ s0)  + D u[t]
// f    = M @ U (chunk-final local states), s0 via 32-step fp32 chunk scan.
__global__ __launch_bounds__(256) void k_scan(const float* __restrict__ xnT,
                                              const float* __restrict__ Lre,
                                              const float* __restrict__ Lim,
                                              const float* __restrict__ Bre,
                                              const float* __restrict__ Bim,
                                              const float* __restrict__ Cre,
                                              const float* __restrict__ Cim,
                                              const float* __restrict__ Dv,
                                              const float* __restrict__ lstep,
                                              __hip_bfloat16* __restrict__ gb,
                                              float* __restrict__ hid,
                                              int interleaved) {
    __shared__ __align__(16) unsigned char ldsb[60672];
    short* ubf = (short*)(ldsb);              // [c][j] bf16, stride 136 (32 rows)
    short* Tm  = (short*)(ldsb + 8704);       // T or A' [row][col] bf16, stride 136 (128 rows)
    float* Ff  = (float*)(ldsb + 43520);      // [c]: re at +0..63, im at +65..128; stride 130 f32
    short* S0s = (short*)(ldsb + 43520);      // overlay: [c][2n] bf16, stride 136
    float* Kt  = (float*)(ldsb + 60160);      // K[128] f32

    int h = blockIdx.x;
    int tid = threadIdx.x;
    int wv = __builtin_amdgcn_readfirstlane(tid) >> 6;   // uniform wave id
    int lane = tid & 63;
    int l15 = lane & 15, q = lane >> 4;
    const float* uh = xnT + (size_t)h * LSEQ;

    float dt = expf(lstep[h]);
    float Dh = Dv[h];

    // per-lane constants for n = lane (used by K, E, scan, hidden)
    float are, aim, bre, bim;
    ssm_consts(Lre, Lim, Bre, Bim, dt, h * NS + lane, are, aim, bre, bim);
    float cre = Cre[h * NS + lane], cim = Cim[h * NS + lane];

    // power ladder for lane's n: Ab^8,16,32,64
    float A8r = are, A8i = aim;
    cmul(A8r, A8i, A8r, A8i); cmul(A8r, A8i, A8r, A8i); cmul(A8r, A8i, A8r, A8i);
    float A16r = A8r, A16i = A8i;  cmul(A16r, A16i, A16r, A16i);
    float A32r = A16r, A32i = A16i; cmul(A32r, A32i, A32r, A32i);
    float A64r = A32r, A64i = A32i; cmul(A64r, A64i, A64r, A64i);

    // ---- stage u -> ubf (bf16) ----
#pragma unroll
    for (int k = 0; k < 4; ++k) {
        int i4 = k * 1024 + tid * 4;
        float4 v = *(const float4*)(uh + i4);
        int c = i4 >> 7, col = i4 & 127;
        unsigned int* d = (unsigned int*)(ubf + c * 136 + col);
        d[0] = pk2(v.x, v.y);
        d[1] = pk2(v.z, v.w);
    }

    // ---- power pass 1: K taps (wave wv covers j in [32wv, 32wv+32)) ----
    {
        float cbre = cre * bre - cim * bim;
        float cbim = cre * bim + cim * bre;
        float pr = 1.f, pi = 0.f;
        if (wv & 1) cmul(pr, pi, A32r, A32i);
        if (wv & 2) cmul(pr, pi, A64r, A64i);
        for (int i = 0; i < 32; ++i) {
            float kj = 2.f * (cbre * pr - cbim * pi);
#pragma unroll
            for (int o = 1; o <= 32; o <<= 1) kj += __shfl_xor(kj, o);
            if (lane == 0) Kt[32 * wv + i] = kj;
            cmul(pr, pi, are, aim);
        }
    }
    __syncthreads();   // ubf + K ready

    // ---- build Toeplitz T (all threads) ----
#pragma unroll 4
    for (int it = 0; it < 64; ++it) {
        int idx = it * 256 + tid;
        int row = idx >> 7, col = idx & 127;
        float kv = Kt[(row - col) & 127];
        Tm[row * 136 + col] = (col <= row) ? b16(kv) : (short)0;
    }

    // ---- GEMM1: F = M @ U  (wave wv = m-tile over states 16wv..16wv+15) ----
    {
        int n2 = 16 * wv + l15;   // this lane's A-row state index
        float are2, aim2, bre2, bim2;
        ssm_consts(Lre, Lim, Bre, Bim, dt, h * NS + n2, are2, aim2, bre2, bim2);
        float B8r = are2, B8i = aim2;
        cmul(B8r, B8i, B8r, B8i); cmul(B8r, B8i, B8r, B8i); cmul(B8r, B8i, B8r, B8i);
        float B16r = B8r, B16i = B8i;  cmul(B16r, B16i, B16r, B16i);
        float B32r = B16r, B32i = B16i; cmul(B32r, B32i, B32r, B32i);
        float B64r = B32r, B64i = B32i; cmul(B64r, B64i, B64r, B64i);

        floatx4 fR[2], fI[2];
#pragma unroll
        for (int nt = 0; nt < 2; ++nt) { fR[nt] = (floatx4){0,0,0,0}; fI[nt] = (floatx4){0,0,0,0}; }

#pragma unroll
        for (int ks = 0; ks < 4; ++ks) {
            int m8 = 15 - 4 * ks - q;      // Abase = Ab^(8*m8)
            float sR = 1.f, sI = 0.f, tR, tI;
            tR = sR * B8r - sI * B8i;  tI = sR * B8i + sI * B8r;
            sR = (m8 & 1) ? tR : sR;   sI = (m8 & 1) ? tI : sI;
            tR = sR * B16r - sI * B16i; tI = sR * B16i + sI * B16r;
            sR = (m8 & 2) ? tR : sR;   sI = (m8 & 2) ? tI : sI;
            tR = sR * B32r - sI * B32i; tI = sR * B32i + sI * B32r;
            sR = (m8 & 4) ? tR : sR;   sI = (m8 & 4) ? tI : sI;
            tR = sR * B64r - sI * B64i; tI = sR * B64i + sI * B64r;
            sR = (m8 & 8) ? tR : sR;   sI = (m8 & 8) ? tI : sI;
            // frag elements e=7..0: M[n2][j=32ks+8q+e] = Bb * Ab^(127-j)
            short8 aR, aI;
            float curR = sR, curI = sI;
#pragma unroll
            for (int e = 7; e >= 0; --e) {
                aR[e] = b16(bre2 * curR - bim2 * curI);
                aI[e] = b16(bre2 * curI + bim2 * curR);
                if (e) cmul(curR, curI, are2, aim2);
            }
#pragma unroll
            for (int nt = 0; nt < 2; ++nt) {
                short8 bf = *(short8*)(ubf + (16 * nt + l15) * 136 + 32 * ks + 8 * q);
                fR[nt] = __builtin_amdgcn_mfma_f32_16x16x32_bf16(aR, bf, fR[nt], 0, 0, 0);
                fI[nt] = __builtin_amdgcn_mfma_f32_16x16x32_bf16(aI, bf, fI[nt], 0, 0, 0);
            }
        }
        // write F_T[c][state]
#pragma unroll
        for (int nt = 0; nt < 2; ++nt) {
            int c = 16 * nt + l15;
            float* fp = Ff + c * 130;
#pragma unroll
            for (int reg = 0; reg < 4; ++reg) {
                int ns = 16 * wv + q * 4 + reg;
                fp[ns]      = fR[nt][reg];
                fp[65 + ns] = fI[nt][reg];
            }
        }
    }
    __syncthreads();   // F and T ready

    // ---- chunk-level scan (wave 0): s0 per chunk (bf16 overlay) + hidden ----
    if (wv == 0) {
        float a128r = A64r, a128i = A64i;
        cmul(a128r, a128i, A64r, A64i);
        float sre = 0.f, sim = 0.f;
        for (int c = 0; c < PC; ++c) {
            float fre = Ff[c * 130 + lane];
            float fim = Ff[c * 130 + 65 + lane];
            // S0 row c write lands strictly below all future F reads (272c+272 <= 520c+520)
            ((unsigned int*)(ldsb + 43520 + 272 * c))[lane] = pk2(sre, sim);
            float nr = fmaf(a128r, sre, fmaf(-a128i, sim, fre));
            float ni = fmaf(a128r, sim, fmaf( a128i, sre, fim));
            sre = nr; sim = ni;
        }
        if (interleaved) {
            ((float2*)hid)[h * NS + lane] = make_float2(sre, sim);
        } else {
            hid[h * NS + lane] = sre;
        }
    }

    // ---- GEMM2a: Y = T @ U  (wave wv: m-tiles 2wv, 2wv+1) ----
    floatx4 Y[2][2];
#pragma unroll
    for (int mi = 0; mi < 2; ++mi)
#pragma unroll
        for (int nt = 0; nt < 2; ++nt) Y[mi][nt] = (floatx4){0, 0, 0, 0};

#pragma unroll
    for (int ks = 0; ks < 4; ++ks) {
        short8 bf0 = *(short8*)(ubf + l15 * 136 + 32 * ks + 8 * q);
        short8 bf1 = *(short8*)(ubf + (16 + l15) * 136 + 32 * ks + 8 * q);
#pragma unroll
        for (int mi = 0; mi < 2; ++mi) {
            int row = 16 * (2 * wv + mi) + l15;
            short8 ta = *(short8*)(Tm + row * 136 + 32 * ks + 8 * q);
            Y[mi][0] = __builtin_amdgcn_mfma_f32_16x16x32_bf16(ta, bf0, Y[mi][0], 0, 0, 0);
            Y[mi][1] = __builtin_amdgcn_mfma_f32_16x16x32_bf16(ta, bf1, Y[mi][1], 0, 0, 0);
        }
    }
    __syncthreads();   // everyone done with T; S0 ready

    // ---- power pass 2: build A' = [Ere | -Eim] over Tm (wave wv: rows 32wv..32wv+32) ----
    {
        float pr = 1.f, pi = 0.f;
        if (wv & 1) cmul(pr, pi, A32r, A32i);
        if (wv & 2) cmul(pr, pi, A64r, A64i);
        cmul(pr, pi, are, aim);            // Ab^(32wv+1)
        for (int i = 0; i < 32; ++i) {
            int t = 32 * wv + i;
            float er =  2.f * (cre * pr - cim * pi);
            float en = -2.f * (cre * pi + cim * pr);
            ((unsigned int*)(ldsb + 8704 + 272 * t))[lane] = pk2(er, en);
            cmul(pr, pi, are, aim);
        }
    }
    __syncthreads();   // A' ready

    // ---- GEMM2b: Y += A' @ S0'  (k = 128 packed 2n) ----
#pragma unroll
    for (int ks = 0; ks < 4; ++ks) {
        short8 sf0 = *(short8*)(S0s + l15 * 136 + 32 * ks + 8 * q);
        short8 sf1 = *(short8*)(S0s + (16 + l15) * 136 + 32 * ks + 8 * q);
#pragma unroll
        for (int mi = 0; mi < 2; ++mi) {
            int row = 16 * (2 * wv + mi) + l15;
            short8 ea = *(short8*)(Tm + row * 136 + 32 * ks + 8 * q);
            Y[mi][0] = __builtin_amdgcn_mfma_f32_16x16x32_bf16(ea, sf0, Y[mi][0], 0, 0, 0);
            Y[mi][1] = __builtin_amdgcn_mfma_f32_16x16x32_bf16(ea, sf1, Y[mi][1], 0, 0, 0);
        }
    }

    // ---- epilogue: + D*u, GELU, scatter gb[l][h] ----
#pragma unroll
    for (int mi = 0; mi < 2; ++mi) {
#pragma unroll
        for (int nt = 0; nt < 2; ++nt) {
#pragma unroll
            for (int reg = 0; reg < 4; ++reg) {
                int t = 16 * (2 * wv + mi) + q * 4 + reg;   // C/D: row=(lane>>4)*4+reg
                int c = 16 * nt + l15;                       // col=lane&15
                int l = c * MC + t;
                float u = uh[l];
                float y = Y[mi][nt][reg] + Dh * u;
                float z = 0.7978845608028654f * fmaf(0.044715f, y * y * y, y);
                float e = __expf(2.f * z);
                float th = 1.f - 2.f / (e + 1.f);
                float gg = 0.5f * y * (1.f + th);
                gb[((size_t)l << 8) + h] = __float2bfloat16(gg);
            }
        }
    }
}

// ---------------- GLU epilogue via MFMA, LDS-free ----------------
__global__ __launch_bounds__(64) void k_glu_mfma(const unsigned short* __restrict__ gbs,
                                                 const unsigned short* __restrict__ w1b,
                                                 const unsigned short* __restrict__ w2b,
                                                 const float* __restrict__ b1v,
                                                 const float* __restrict__ b2v,
                                                 const float* __restrict__ x,
                                                 float* __restrict__ out) {
    int bx = blockIdx.x;
    int m0 = (bx >> 3) * 32;
    int n0 = (bx & 7) * 32;
    int lane = threadIdx.x;
    int t = lane & 15, q = lane >> 4;

    floatx4 acc[2][2][2];
#pragma unroll
    for (int a = 0; a < 2; ++a)
#pragma unroll
        for (int b = 0; b < 2; ++b)
#pragma unroll
            for (int g = 0; g < 2; ++g)
                acc[a][b][g] = (floatx4){0.f, 0.f, 0.f, 0.f};

    const unsigned short* A0  = gbs + (size_t)(m0 + t) * HDIM + q * 8;
    const unsigned short* A1  = A0 + 16 * HDIM;
    const unsigned short* B10 = w1b + (size_t)(n0 + t) * HDIM + q * 8;
    const unsigned short* B11 = B10 + 16 * HDIM;
    const unsigned short* B20 = w2b + (size_t)(n0 + t) * HDIM + q * 8;
    const unsigned short* B21 = B20 + 16 * HDIM;

#pragma unroll
    for (int ks = 0; ks < 8; ++ks) {
        int off = ks * 32;
        short8 a0  = *(const short8*)(A0  + off);
        short8 a1  = *(const short8*)(A1  + off);
        short8 b10 = *(const short8*)(B10 + off);
        short8 b11 = *(const short8*)(B11 + off);
        short8 b20 = *(const short8*)(B20 + off);
        short8 b21 = *(const short8*)(B21 + off);
        acc[0][0][0] = __builtin_amdgcn_mfma_f32_16x16x32_bf16(a0, b10, acc[0][0][0], 0, 0, 0);
        acc[0][1][0] = __builtin_amdgcn_mfma_f32_16x16x32_bf16(a0, b11, acc[0][1][0], 0, 0, 0);
        acc[1][0][0] = __builtin_amdgcn_mfma_f32_16x16x32_bf16(a1, b10, acc[1][0][0], 0, 0, 0);
        acc[1][1][0] = __builtin_amdgcn_mfma_f32_16x16x32_bf16(a1, b11, acc[1][1][0], 0, 0, 0);
        acc[0][0][1] = __builtin_amdgcn_mfma_f32_16x16x32_bf16(a0, b20, acc[0][0][1], 0, 0, 0);
        acc[0][1][1] = __builtin_amdgcn_mfma_f32_16x16x32_bf16(a0, b21, acc[0][1][1], 0, 0, 0);
        acc[1][0][1] = __builtin_amdgcn_mfma_f32_16x16x32_bf16(a1, b20, acc[1][0][1], 0, 0, 0);
        acc[1][1][1] = __builtin_amdgcn_mfma_f32_16x16x32_bf16(a1, b21, acc[1][1][1], 0, 0, 0);
    }

#pragma unroll
    for (int nt = 0; nt < 2; ++nt) {
        int hh = n0 + nt * 16 + t;
        float bb1 = b1v[hh], bb2 = b2v[hh];
#pragma unroll
        for (int mt = 0; mt < 2; ++mt) {
#pragma unroll
            for (int reg = 0; reg < 4; ++reg) {
                int l = m0 + mt * 16 + q * 4 + reg;
                float a  = acc[mt][nt][0][reg] + bb1;
                float sg = 1.f / (1.f + __expf(-(acc[mt][nt][1][reg] + bb2)));
                out[(size_t)l * HDIM + hh] = fmaf(a, sg, x[(size_t)l * HDIM + hh]);
            }
        }
    }
}

extern "C" void kernel_launch(void* const* d_in, const int* in_sizes, int n_in,
                              void* d_out, int out_size, void* d_ws, size_t ws_size,
                              hipStream_t stream) {
    (void)in_sizes; (void)n_in; (void)ws_size;
    const float* x     = (const float*)d_in[0];
    const float* Lre   = (const float*)d_in[1];
    const float* Lim   = (const float*)d_in[2];
    const float* Bre   = (const float*)d_in[3];
    const float* Bim   = (const float*)d_in[4];
    const float* Cre   = (const float*)d_in[5];
    const float* Cim   = (const float*)d_in[6];
    const float* Dv    = (const float*)d_in[7];
    const float* lstep = (const float*)d_in[8];
    const float* lnw   = (const float*)d_in[9];
    const float* lnb   = (const float*)d_in[10];
    const float* W1    = (const float*)d_in[11];
    const float* b1    = (const float*)d_in[12];
    const float* W2    = (const float*)d_in[13];
    const float* b2    = (const float*)d_in[14];

    float* ws   = (float*)d_ws;
    float* xnT  = ws;                                     // H*L fp32
    unsigned short* gb  = (unsigned short*)(xnT + (size_t)HDIM * LSEQ);  // L*H bf16
    unsigned short* w1b = gb + (size_t)LSEQ * HDIM;       // H*H bf16
    unsigned short* w2b = w1b + HDIM * HDIM;              // H*H bf16

    int interleaved = (out_size == LSEQ * HDIM + 2 * HDIM * NS) ? 1 : 0;
    float* hid  = (float*)d_out;
    float* outp = (float*)d_out + (interleaved ? 2 * HDIM * NS : HDIM * NS);

    k_pre      <<<256 + 64, 256, 0, stream>>>(x, lnw, lnb, W1, W2, xnT, w1b, w2b);
    k_scan     <<<HDIM, 256, 0, stream>>>(xnT, Lre, Lim, Bre, Bim, Cre, Cim,
                                          Dv, lstep, (__hip_bfloat16*)gb, hid, interleaved);
    k_glu_mfma <<<128 * 8, 64, 0, stream>>>(gb, w1b, w2b, b1, b2, x, outp);
}

// Round 6
// 114.555 us; speedup vs baseline: 1.2134x; 1.0728x over previous
//
#include <hip/hip_runtime.h>
#include <hip/hip_bf16.h>

#define LSEQ 4096
#define HDIM 256
#define NS   64
#define PC   32    // number of chunks
#define MC   128   // chunk length (PC*MC == LSEQ)

typedef __attribute__((ext_vector_type(8))) short short8;
typedef __attribute__((ext_vector_type(4))) float floatx4;

__device__ __forceinline__ short b16(float x) {
    __hip_bfloat16 h = __float2bfloat16(x);
    return *(reinterpret_cast<short*>(&h));
}
__device__ __forceinline__ unsigned int pk2(float a, float b) {
    return (unsigned int)(unsigned short)b16(a) | ((unsigned int)(unsigned short)b16(b) << 16);
}
__device__ __forceinline__ void cmul(float& xr, float& xi, float yr, float yi) {
    float r = xr * yr - xi * yi;
    float i = xr * yi + xi * yr;
    xr = r; xi = i;
}

// ---------------- fused LN (stats+normalize+transpose) + W->bf16 conv ----------------
__global__ __launch_bounds__(256) void k_pre(const float* __restrict__ x,
                                             const float* __restrict__ lnw,
                                             const float* __restrict__ lnb,
                                             const float* __restrict__ W1,
                                             const float* __restrict__ W2,
                                             float* __restrict__ xnT,
                                             unsigned short* __restrict__ w1b,
                                             unsigned short* __restrict__ w2b) {
    int t = threadIdx.x;
    if (blockIdx.x >= 256) {   // weight conversion tail blocks
        int g = (blockIdx.x - 256) * 256 + t;
        float4 a = ((const float4*)W1)[g];
        float4 c = ((const float4*)W2)[g];
        ushort4 o1, o2;
        o1.x = (unsigned short)b16(a.x); o1.y = (unsigned short)b16(a.y);
        o1.z = (unsigned short)b16(a.z); o1.w = (unsigned short)b16(a.w);
        o2.x = (unsigned short)b16(c.x); o2.y = (unsigned short)b16(c.y);
        o2.z = (unsigned short)b16(c.z); o2.w = (unsigned short)b16(c.w);
        ((ushort4*)w1b)[g] = o1;
        ((ushort4*)w2b)[g] = o2;
        return;
    }
    __shared__ float tile[16][257];
    __shared__ float smu[16], srs[16];
    int l0 = blockIdx.x * 16;
#pragma unroll
    for (int i = 0; i < 16; ++i)
        tile[i][t] = x[(size_t)(l0 + i) * HDIM + t];
    __syncthreads();
    int wv = t >> 6, lane = t & 63;
#pragma unroll
    for (int k = 0; k < 4; ++k) {
        int i = wv * 4 + k;
        float s = 0.f, s2 = 0.f;
#pragma unroll
        for (int q = 0; q < 4; ++q) {
            float v = tile[i][lane + 64 * q];
            s += v; s2 += v * v;
        }
#pragma unroll
        for (int o = 32; o; o >>= 1) {
            s  += __shfl_xor(s, o);
            s2 += __shfl_xor(s2, o);
        }
        if (lane == 0) {
            float m = s * (1.0f / HDIM);
            smu[i] = m;
            srs[i] = rsqrtf(s2 * (1.0f / HDIM) - m * m + 1e-5f);
        }
    }
    __syncthreads();
    float wh = lnw[t], bh = lnb[t];
    float o[16];
#pragma unroll
    for (int i = 0; i < 16; ++i)
        o[i] = (tile[i][t] - smu[i]) * srs[i] * wh + bh;
    float4* dst = (float4*)(xnT + (size_t)t * LSEQ + l0);
#pragma unroll
    for (int k = 0; k < 4; ++k)
        dst[k] = make_float4(o[4 * k], o[4 * k + 1], o[4 * k + 2], o[4 * k + 3]);
}

// ---------------- shared constant computation ----------------
__device__ __forceinline__ void ssm_consts(const float* Lre, const float* Lim,
                                           const float* Bre, const float* Bim,
                                           float dt, int idx,
                                           float& are, float& aim, float& bre, float& bim) {
    float lre = Lre[idx], lim = Lim[idx];
    float er = expf(lre * dt);
    float sa, ca;
    sincosf(lim * dt, &sa, &ca);
    are = er * ca; aim = er * sa;
    float inv = 1.0f / (lre * lre + lim * lim);
    float nre = are - 1.0f, nim = aim;
    float tre = (nre * lre + nim * lim) * inv;
    float tim = (nim * lre - nre * lim) * inv;
    float br = Bre[idx], bi = Bim[idx];
    bre = tre * br - tim * bi;
    bim = tre * bi + tim * br;
}

// ---------------- MFMA-formulated SSM: one block (16 waves) per h ----------------
// y[t] = sum_{j<=t} K[t-j] u[j]  (Toeplitz GEMM)  + Re(E @ s0)  + D u[t]
// F = M @ U (chunk-final local states), s0 via 32-step fp32 chunk scan.
// 16 waves: each owns one 16x16 MFMA tile per GEMM; M/A' built in parallel.
__global__ __launch_bounds__(1024) void k_scan(const float* __restrict__ xnT,
                                               const float* __restrict__ Lre,
                                               const float* __restrict__ Lim,
                                               const float* __restrict__ Bre,
                                               const float* __restrict__ Bim,
                                               const float* __restrict__ Cre,
                                               const float* __restrict__ Cim,
                                               const float* __restrict__ Dv,
                                               const float* __restrict__ lstep,
                                               __hip_bfloat16* __restrict__ gb,
                                               float* __restrict__ hid,
                                               int interleaved) {
    __shared__ __align__(16) unsigned char ldsb[60672];
    short* ubf = (short*)(ldsb);              // [c][j] bf16, stride 136 (32 rows)
    short* Tm  = (short*)(ldsb + 8704);       // M -> Toeplitz T -> A' ; 128 rows, stride 136
    float* Ff  = (float*)(ldsb + 43520);      // [c]: re at +0..63, im at +65..128; stride 130 f32
    short* S0s = (short*)(ldsb + 43520);      // overlay: [c][2n] bf16, stride 136
    float* Kt  = (float*)(ldsb + 60160);      // K[128] f32

    int h = blockIdx.x;
    int tid = threadIdx.x;
    int wv = __builtin_amdgcn_readfirstlane(tid) >> 6;   // uniform wave id 0..15
    int lane = tid & 63;
    int l15 = lane & 15, q = lane >> 4;
    int mt = wv >> 1, nt = wv & 1;            // this wave's tile (rows 16mt.., chunks 16nt..)
    const float* uh = xnT + (size_t)h * LSEQ;

    float dt = expf(lstep[h]);
    float Dh = Dv[h];

    // per-lane constants for n = lane
    float are, aim, bre, bim;
    ssm_consts(Lre, Lim, Bre, Bim, dt, h * NS + lane, are, aim, bre, bim);
    float cre = Cre[h * NS + lane], cim = Cim[h * NS + lane];

    // power ladder: Ab^2..Ab^64 (per-lane n)
    float A2r = are, A2i = aim;   cmul(A2r, A2i, are, aim);
    float A4r = A2r, A4i = A2i;   cmul(A4r, A4i, A2r, A2i);
    float A8r = A4r, A8i = A4i;   cmul(A8r, A8i, A4r, A4i);
    float A16r = A8r, A16i = A8i;  cmul(A16r, A16i, A8r, A8i);
    float A32r = A16r, A32i = A16i; cmul(A32r, A32i, A16r, A16i);
    float A64r = A32r, A64i = A32i; cmul(A64r, A64i, A32r, A32i);

    // ---- stage u -> ubf (bf16): one float4 per thread ----
    {
        int i4 = tid * 4;
        float4 v = *(const float4*)(uh + i4);
        int c = i4 >> 7, col = i4 & 127;
        unsigned int* d = (unsigned int*)(ubf + c * 136 + col);
        d[0] = pk2(v.x, v.y);
        d[1] = pk2(v.z, v.w);
    }

    // ---- K taps: wave wv computes taps 8wv..8wv+8 ----
    {
        float cbre = cre * bre - cim * bim;
        float cbim = cre * bim + cim * bre;
        float pr = 1.f, pi = 0.f;                 // Ab^(8wv)
        if (wv & 1) cmul(pr, pi, A8r, A8i);
        if (wv & 2) cmul(pr, pi, A16r, A16i);
        if (wv & 4) cmul(pr, pi, A32r, A32i);
        if (wv & 8) cmul(pr, pi, A64r, A64i);
#pragma unroll
        for (int i = 0; i < 8; ++i) {
            float kj = 2.f * (cbre * pr - cbim * pi);
#pragma unroll
            for (int o = 1; o <= 32; o <<= 1) kj += __shfl_xor(kj, o);
            if (lane == 0) Kt[8 * wv + i] = kj;
            cmul(pr, pi, are, aim);
        }
    }

    // ---- M build (parallel): thread (n=lane) fills M[n][j], j in [8wv, 8wv+8) ----
    // M[n][j] = Bb * Ab^(127-j); iterate j downward so exponent climbs by 1.
    {
        int v = 15 - wv;
        float pr = 1.f, pi = 0.f;                 // Ab^(8(15-wv)) = Ab^(120-8wv)
        if (v & 1) cmul(pr, pi, A8r, A8i);
        if (v & 2) cmul(pr, pi, A16r, A16i);
        if (v & 4) cmul(pr, pi, A32r, A32i);
        if (v & 8) cmul(pr, pi, A64r, A64i);
        short8 rr, ri;
#pragma unroll
        for (int i = 0; i < 8; ++i) {             // j = 8wv+7-i, e = 120-8wv+i
            rr[7 - i] = b16(bre * pr - bim * pi);
            ri[7 - i] = b16(bre * pi + bim * pr);
            cmul(pr, pi, are, aim);
        }
        *(short8*)(Tm + lane * 136 + 8 * wv) = rr;          // M_re rows 0..63
        *(short8*)(Tm + (64 + lane) * 136 + 8 * wv) = ri;   // M_im rows 64..127
    }
    __syncthreads();   // ubf, Kt, M ready

    // ---- GEMM1: F = M @ U ; wave wv -> 16x16 tile ----
    {
        floatx4 fa = (floatx4){0.f, 0.f, 0.f, 0.f};
#pragma unroll
        for (int ks = 0; ks < 4; ++ks) {
            short8 am = *(short8*)(Tm + (16 * mt + l15) * 136 + 32 * ks + 8 * q);
            short8 bu = *(short8*)(ubf + (16 * nt + l15) * 136 + 32 * ks + 8 * q);
            fa = __builtin_amdgcn_mfma_f32_16x16x32_bf16(am, bu, fa, 0, 0, 0);
        }
        int c = 16 * nt + l15;
        float* fp = Ff + c * 130;
        int sbase = 16 * mt + 4 * q;              // state index (mt<4: re, mt>=4: im)
#pragma unroll
        for (int reg = 0; reg < 4; ++reg) {
            int s = sbase + reg;
            fp[(mt < 4) ? s : (1 + s)] = fa[reg]; // im block starts at offset 65 = 1+64
        }
    }
    __syncthreads();   // F ready; M consumed

    // ---- concurrent: waves 1..15 build Toeplitz T; wave 0 runs the chunk scan ----
    if (wv != 0) {
#pragma unroll
        for (int it = 0; it < 18; ++it) {
            int idx = it * 960 + (tid - 64);
            if (idx < 128 * 128) {
                int row = idx >> 7, col = idx & 127;
                float kv = Kt[(row - col) & 127];
                Tm[row * 136 + col] = (col <= row) ? b16(kv) : (short)0;
            }
        }
    } else {
        // chunk-level scan: s0 per chunk (bf16 overlay under consumed F rows) + hidden
        float a128r = A64r, a128i = A64i;
        cmul(a128r, a128i, A64r, A64i);
        float sre = 0.f, sim = 0.f;
        for (int c = 0; c < PC; ++c) {
            float fre = Ff[c * 130 + lane];
            float fim = Ff[c * 130 + 65 + lane];
            ((unsigned int*)(ldsb + 43520 + 272 * c))[lane] = pk2(sre, sim);
            float nr = fmaf(a128r, sre, fmaf(-a128i, sim, fre));
            float ni = fmaf(a128r, sim, fmaf( a128i, sre, fim));
            sre = nr; sim = ni;
        }
        if (interleaved) {
            ((float2*)hid)[h * NS + lane] = make_float2(sre, sim);
        } else {
            hid[h * NS + lane] = sre;
        }
    }
    __syncthreads();   // T and S0 ready

    // ---- GEMM2a: Y = T @ U ; wave wv -> 16x16 tile ----
    floatx4 Y = (floatx4){0.f, 0.f, 0.f, 0.f};
#pragma unroll
    for (int ks = 0; ks < 4; ++ks) {
        short8 ta = *(short8*)(Tm + (16 * mt + l15) * 136 + 32 * ks + 8 * q);
        short8 bu = *(short8*)(ubf + (16 * nt + l15) * 136 + 32 * ks + 8 * q);
        Y = __builtin_amdgcn_mfma_f32_16x16x32_bf16(ta, bu, Y, 0, 0, 0);
    }
    __syncthreads();   // T consumed

    // ---- A' build: wave wv -> rows 8wv..8wv+8 ; A'[t][2n,2n+1] = 2Re/-2Im(C*Ab^(t+1)) ----
    {
        float pr = are, pi = aim;                 // Ab^(8wv+1)
        if (wv & 1) cmul(pr, pi, A8r, A8i);
        if (wv & 2) cmul(pr, pi, A16r, A16i);
        if (wv & 4) cmul(pr, pi, A32r, A32i);
        if (wv & 8) cmul(pr, pi, A64r, A64i);
#pragma unroll
        for (int i = 0; i < 8; ++i) {
            int t = 8 * wv + i;
            float er =  2.f * (cre * pr - cim * pi);
            float en = -2.f * (cre * pi + cim * pr);
            ((unsigned int*)(ldsb + 8704 + 272 * t))[lane] = pk2(er, en);
            cmul(pr, pi, are, aim);
        }
    }
    __syncthreads();   // A' ready

    // ---- GEMM2b: Y += A' @ S0' (k = 128 packed 2n) ----
#pragma unroll
    for (int ks = 0; ks < 4; ++ks) {
        short8 ea = *(short8*)(Tm + (16 * mt + l15) * 136 + 32 * ks + 8 * q);
        short8 sf = *(short8*)(S0s + (16 * nt + l15) * 136 + 32 * ks + 8 * q);
        Y = __builtin_amdgcn_mfma_f32_16x16x32_bf16(ea, sf, Y, 0, 0, 0);
    }

    // ---- epilogue: + D*u, GELU, scatter gb[l][h] ----
    {
        int c = 16 * nt + l15;
#pragma unroll
        for (int reg = 0; reg < 4; ++reg) {
            int t = 16 * mt + 4 * q + reg;        // C/D: row=(lane>>4)*4+reg, col=lane&15
            int l = c * MC + t;
            float u = uh[l];
            float y = Y[reg] + Dh * u;
            float z = 0.7978845608028654f * fmaf(0.044715f, y * y * y, y);
            float e = __expf(2.f * z);
            float th = 1.f - 2.f / (e + 1.f);
            float gg = 0.5f * y * (1.f + th);
            gb[((size_t)l << 8) + h] = __float2bfloat16(gg);
        }
    }
}

// ---------------- GLU epilogue via MFMA, LDS-free ----------------
__global__ __launch_bounds__(64) void k_glu_mfma(const unsigned short* __restrict__ gbs,
                                                 const unsigned short* __restrict__ w1b,
                                                 const unsigned short* __restrict__ w2b,
                                                 const float* __restrict__ b1v,
                                                 const float* __restrict__ b2v,
                                                 const float* __restrict__ x,
                                                 float* __restrict__ out) {
    int bx = blockIdx.x;
    int m0 = (bx >> 3) * 32;
    int n0 = (bx & 7) * 32;
    int lane = threadIdx.x;
    int t = lane & 15, q = lane >> 4;

    floatx4 acc[2][2][2];
#pragma unroll
    for (int a = 0; a < 2; ++a)
#pragma unroll
        for (int b = 0; b < 2; ++b)
#pragma unroll
            for (int g = 0; g < 2; ++g)
                acc[a][b][g] = (floatx4){0.f, 0.f, 0.f, 0.f};

    const unsigned short* A0  = gbs + (size_t)(m0 + t) * HDIM + q * 8;
    const unsigned short* A1  = A0 + 16 * HDIM;
    const unsigned short* B10 = w1b + (size_t)(n0 + t) * HDIM + q * 8;
    const unsigned short* B11 = B10 + 16 * HDIM;
    const unsigned short* B20 = w2b + (size_t)(n0 + t) * HDIM + q * 8;
    const unsigned short* B21 = B20 + 16 * HDIM;

#pragma unroll
    for (int ks = 0; ks < 8; ++ks) {
        int off = ks * 32;
        short8 a0  = *(const short8*)(A0  + off);
        short8 a1  = *(const short8*)(A1  + off);
        short8 b10 = *(const short8*)(B10 + off);
        short8 b11 = *(const short8*)(B11 + off);
        short8 b20 = *(const short8*)(B20 + off);
        short8 b21 = *(const short8*)(B21 + off);
        acc[0][0][0] = __builtin_amdgcn_mfma_f32_16x16x32_bf16(a0, b10, acc[0][0][0], 0, 0, 0);
        acc[0][1][0] = __builtin_amdgcn_mfma_f32_16x16x32_bf16(a0, b11, acc[0][1][0], 0, 0, 0);
        acc[1][0][0] = __builtin_amdgcn_mfma_f32_16x16x32_bf16(a1, b10, acc[1][0][0], 0, 0, 0);
        acc[1][1][0] = __builtin_amdgcn_mfma_f32_16x16x32_bf16(a1, b11, acc[1][1][0], 0, 0, 0);
        acc[0][0][1] = __builtin_amdgcn_mfma_f32_16x16x32_bf16(a0, b20, acc[0][0][1], 0, 0, 0);
        acc[0][1][1] = __builtin_amdgcn_mfma_f32_16x16x32_bf16(a0, b21, acc[0][1][1], 0, 0, 0);
        acc[1][0][1] = __builtin_amdgcn_mfma_f32_16x16x32_bf16(a1, b20, acc[1][0][1], 0, 0, 0);
        acc[1][1][1] = __builtin_amdgcn_mfma_f32_16x16x32_bf16(a1, b21, acc[1][1][1], 0, 0, 0);
    }

#pragma unroll
    for (int nt = 0; nt < 2; ++nt) {
        int hh = n0 + nt * 16 + t;
        float bb1 = b1v[hh], bb2 = b2v[hh];
#pragma unroll
        for (int mt = 0; mt < 2; ++mt) {
#pragma unroll
            for (int reg = 0; reg < 4; ++reg) {
                int l = m0 + mt * 16 + q * 4 + reg;
                float a  = acc[mt][nt][0][reg] + bb1;
                float sg = 1.f / (1.f + __expf(-(acc[mt][nt][1][reg] + bb2)));
                out[(size_t)l * HDIM + hh] = fmaf(a, sg, x[(size_t)l * HDIM + hh]);
            }
        }
    }
}

extern "C" void kernel_launch(void* const* d_in, const int* in_sizes, int n_in,
                              void* d_out, int out_size, void* d_ws, size_t ws_size,
                              hipStream_t stream) {
    (void)in_sizes; (void)n_in; (void)ws_size;
    const float* x     = (const float*)d_in[0];
    const float* Lre   = (const float*)d_in[1];
    const float* Lim   = (const float*)d_in[2];
    const float* Bre   = (const float*)d_in[3];
    const float* Bim   = (const float*)d_in[4];
    const float* Cre   = (const float*)d_in[5];
    const float* Cim   = (const float*)d_in[6];
    const float* Dv    = (const float*)d_in[7];
    const float* lstep = (const float*)d_in[8];
    const float* lnw   = (const float*)d_in[9];
    const float* lnb   = (const float*)d_in[10];
    const float* W1    = (const float*)d_in[11];
    const float* b1    = (const float*)d_in[12];
    const float* W2    = (const float*)d_in[13];
    const float* b2    = (const float*)d_in[14];

    float* ws   = (float*)d_ws;
    float* xnT  = ws;                                     // H*L fp32
    unsigned short* gb  = (unsigned short*)(xnT + (size_t)HDIM * LSEQ);  // L*H bf16
    unsigned short* w1b = gb + (size_t)LSEQ * HDIM;       // H*H bf16
    unsigned short* w2b = w1b + HDIM * HDIM;              // H*H bf16

    int interleaved = (out_size == LSEQ * HDIM + 2 * HDIM * NS) ? 1 : 0;
    float* hid  = (float*)d_out;
    float* outp = (float*)d_out + (interleaved ? 2 * HDIM * NS : HDIM * NS);

    k_pre      <<<256 + 64, 256, 0, stream>>>(x, lnw, lnb, W1, W2, xnT, w1b, w2b);
    k_scan     <<<HDIM, 1024, 0, stream>>>(xnT, Lre, Lim, Bre, Bim, Cre, Cim,
                                           Dv, lstep, (__hip_bfloat16*)gb, hid, interleaved);
    k_glu_mfma <<<128 * 8, 64, 0, stream>>>(gb, w1b, w2b, b1, b2, x, outp);
}